// Round 9
// baseline (67.416 us; speedup 1.0000x reference)
//
#include <hip/hip_runtime.h>
#include <hip/hip_bf16.h>
#include <math.h>

#define FDIM  128
#define BATCH 4096
#define CNUM  10000

typedef __attribute__((ext_vector_type(8))) short short8;   // 8 bf16 = 4 VGPRs (MFMA A/B frag)
typedef __attribute__((ext_vector_type(4))) float f32x4;    // MFMA C/D frag / float4 store

// ---------------- ws layout (bytes) ----------------
#define WS_FEATB 0            // 4096*128 bf16  = 1048576
#define WS_WB    1048576      // 10000*128 bf16 = 2560000
#define WS_F2    3608576      // 4096 f32
#define WS_W2    3624960      // 10000 f32
#define WS_COR   3664960      // 4096 f32

// exp(-m/1.8) = 2^(-m * C2);  C2 = 1/(1.8*ln2)
#define C2 0.80178372573096f

// async global->LDS, 16B per lane, literal size
#define GL2LDS(g, l) __builtin_amdgcn_global_load_lds(                      \
    (const __attribute__((address_space(1))) void*)(g),                     \
    (__attribute__((address_space(3))) void*)(l), 16, 0, 0)

// Kernel 1: fused prep (f32->bf16 convert + row norms) and cor gather.
__global__ void prep_cor_kernel(const float* __restrict__ feat,
                                const float* __restrict__ weights,
                                const int* __restrict__ label,
                                __hip_bfloat16* __restrict__ featb,
                                __hip_bfloat16* __restrict__ wb,
                                float* __restrict__ f2,
                                float* __restrict__ w2,
                                float* __restrict__ cor) {
    int gw   = (blockIdx.x * blockDim.x + threadIdx.x) >> 6;
    int lane = threadIdx.x & 63;
    if (gw < BATCH + CNUM) {
        const float* src;
        __hip_bfloat16* dst;
        float* nrm;
        if (gw < BATCH) { src = feat    + (size_t)gw * FDIM; dst = featb + (size_t)gw * FDIM; nrm = f2 + gw; }
        else            { int r = gw - BATCH;
                          src = weights + (size_t)r  * FDIM; dst = wb    + (size_t)r  * FDIM; nrm = w2 + r; }
        float2 v = ((const float2*)src)[lane];
        __hip_bfloat162 b2;
        b2.x = __float2bfloat16(v.x);
        b2.y = __float2bfloat16(v.y);
        ((__hip_bfloat162*)dst)[lane] = b2;
        float ss = v.x * v.x + v.y * v.y;
        #pragma unroll
        for (int off = 32; off; off >>= 1) ss += __shfl_down(ss, off, 64);
        if (lane == 0) *nrm = ss;
    } else {
        int s = gw - (BATCH + CNUM);
        if (s >= BATCH) return;
        int lab = label[s];
        float2 f = ((const float2*)(feat    + (size_t)s   * FDIM))[lane];
        float2 w = ((const float2*)(weights + (size_t)lab * FDIM))[lane];
        float dx = f.x - w.x, dy = f.y - w.y;
        float ss = dx * dx + dy * dy;
        #pragma unroll
        for (int off = 32; off; off >>= 1) ss += __shfl_down(ss, off, 64);
        if (lane == 0) cor[s] = __expf(-ss * (1.0f / 1.8f));
    }
}

// Kernel 2: persistent double-buffered band-sweep GEMM, 2 blocks/CU.
// Identical to R8 except: output stores are NONTEMPORAL (bypass L2).
// Mechanism: (a) HBM writes at 64B-sector granularity -> odd-row 512B
// chunks (stride 40000 = 64 mod 128) no longer cost 5 x 128B lines;
// (b) out stream stops churning L2, operand tiles stay resident.
__launch_bounds__(512, 4)
__global__ void gemm_kernel(const __hip_bfloat16* __restrict__ featb,
                            const __hip_bfloat16* __restrict__ wb,
                            const float* __restrict__ f2,
                            const float* __restrict__ w2,
                            const float* __restrict__ cor,
                            float* __restrict__ out) {
    __shared__ __align__(16) char lds[65536];    // A double buffer: buf0 | buf1
    __shared__ float red[8];

    int bx   = blockIdx.x;
    int band = bx & 31;            // 32 bands x 128 batch rows
    int cg   = bx >> 5;            // 16 class-groups, tiles t = it*16+cg
    int tid  = threadIdx.x;
    int wid  = tid >> 6;
    int lane = tid & 63;
    int r16  = lane & 15;
    int kh   = lane >> 4;
    int aoff = (wid & 1) * 64;     // class half within 128-tile
    int boff = (wid >> 1) * 32;    // row quarter within 128-band

    const char* Ab = (const char*)wb;

    // ---- prologue: stage tile t=cg into buf0 ----
    #pragma unroll
    for (int p = 0; p < 4; ++p) {
        int idx = tid + p * 512;
        int row = idx >> 4, chk = idx & 15;
        int gc = cg * 128 + row; gc = gc < CNUM ? gc : CNUM - 1;
        GL2LDS(Ab + (size_t)gc * 256 + (chk ^ (row & 7)) * 16, lds + idx * 16);
    }

    // ---- deterministic scale reduction (identical in every block),
    //      hidden under the staging wait ----
    {
        float s = 0.0f;
        #pragma unroll
        for (int i = 0; i < BATCH / 512; ++i) s += cor[tid + i * 512];
        #pragma unroll
        for (int off = 32; off; off >>= 1) s += __shfl_down(s, off, 64);
        if (lane == 0) red[wid] = s;
    }

    float f2n[2];
    #pragma unroll
    for (int n = 0; n < 2; ++n) f2n[n] = f2[band * 128 + boff + n * 16 + r16];

    __syncthreads();   // full drain (staging + red visible)

    float tot = 0.0f;
    #pragma unroll
    for (int i = 0; i < 8; ++i) tot += red[i];
    float avg = fmaxf(tot * (1.0f / BATCH), 0.5f);
    float ls2 = log2f(logf((float)(CNUM - 1)) / avg);

    // ---- B fragments straight from global (featb is L2-resident) ----
    const char* Bb = (const char*)featb;
    short8 bfrag[4][2];
    #pragma unroll
    for (int kk = 0; kk < 4; ++kk)
        #pragma unroll
        for (int n = 0; n < 2; ++n) {
            int row = band * 128 + boff + n * 16 + r16;
            bfrag[kk][n] = *(const short8*)(Bb + (size_t)row * 256 + kk * 64 + kh * 16);
        }

    #pragma unroll
    for (int it = 0; it < 5; ++it) {
        int t   = it * 16 + cg;        // interleaved tile index
        int cur = it & 1;

        // prefetch next tile into the other buffer (pinned before compute)
        if (it < 4) {
            int tn = t + 16;
            #pragma unroll
            for (int p = 0; p < 4; ++p) {
                int idx = tid + p * 512;
                int row = idx >> 4, chk = idx & 15;
                int gc = tn * 128 + row; gc = gc < CNUM ? gc : CNUM - 1;
                GL2LDS(Ab + (size_t)gc * 256 + (chk ^ (row & 7)) * 16,
                       lds + (cur ^ 1) * 32768 + idx * 16);
            }
        }
        __builtin_amdgcn_sched_barrier(0);   // prefetch issued before compute

        // ---- compute from current buffer ----
        const char* Abuf = lds + cur * 32768;
        f32x4 acc[4][2];
        #pragma unroll
        for (int m = 0; m < 4; ++m)
            #pragma unroll
            for (int n = 0; n < 2; ++n) acc[m][n] = (f32x4){0.f, 0.f, 0.f, 0.f};

        #pragma unroll
        for (int kk = 0; kk < 4; ++kk) {
            short8 a[4];
            #pragma unroll
            for (int m = 0; m < 4; ++m) {
                int row = aoff + m * 16 + r16;
                int c = (kk * 4 + kh) ^ (row & 7);
                a[m] = *(const short8*)(Abuf + row * 256 + c * 16);
            }
            #pragma unroll
            for (int m = 0; m < 4; ++m)
                #pragma unroll
                for (int n = 0; n < 2; ++n)
                    acc[m][n] = __builtin_amdgcn_mfma_f32_16x16x32_bf16(a[m], bfrag[kk][n], acc[m][n], 0, 0, 0);
        }

        // ---- epilogue per-m (w4 just-in-time), NONTEMPORAL stores ----
        int mbase = t * 128 + aoff;
        #pragma unroll
        for (int m = 0; m < 4; ++m) {
            int cm0 = mbase + m * 16 + kh * 4;     // first of 4 consecutive classes
            bool ok = cm0 < CNUM;                   // cm0,CNUM % 4 == 0 -> no straddle
            f32x4 w4 = *(const f32x4*)(w2 + (ok ? cm0 : 0));
            #pragma unroll
            for (int n = 0; n < 2; ++n) {
                f32x4 v;
                #pragma unroll
                for (int r = 0; r < 4; ++r) {
                    float mt2 = fmaf(-2.0f, acc[m][n][r], f2n[n] + w4[r]);
                    mt2 = fmaxf(mt2, 0.0f);
                    v[r] = exp2f(fmaf(mt2, -C2, ls2));
                }
                if (ok) {
                    size_t rg = (size_t)(band * 128 + boff + n * 16 + r16);
                    __builtin_nontemporal_store(v, (f32x4*)(out + rg * CNUM + cm0));
                }
            }
        }

        // counted-vmcnt barrier: retire prefetch + w4 (order-independent),
        // keep this iter's 8 stores in flight under the next compute.
        asm volatile("s_waitcnt vmcnt(8)" ::: "memory");
        __builtin_amdgcn_sched_barrier(0);
        __builtin_amdgcn_s_barrier();
    }
}

extern "C" void kernel_launch(void* const* d_in, const int* in_sizes, int n_in,
                              void* d_out, int out_size, void* d_ws, size_t ws_size,
                              hipStream_t stream) {
    (void)in_sizes; (void)n_in; (void)out_size; (void)ws_size;
    const float* feat    = (const float*)d_in[0];
    const float* weights = (const float*)d_in[1];
    const int*   label   = (const int*)d_in[2];
    float* out = (float*)d_out;
    char*  ws  = (char*)d_ws;

    __hip_bfloat16* featb = (__hip_bfloat16*)(ws + WS_FEATB);
    __hip_bfloat16* wb    = (__hip_bfloat16*)(ws + WS_WB);
    float* f2  = (float*)(ws + WS_F2);
    float* w2  = (float*)(ws + WS_W2);
    float* cor = (float*)(ws + WS_COR);

    const int total_waves = BATCH + CNUM + BATCH;
    prep_cor_kernel<<<(total_waves + 3) / 4, 256, 0, stream>>>(
        feat, weights, label, featb, wb, f2, w2, cor);

    gemm_kernel<<<512, 512, 0, stream>>>(featb, wb, f2, w2, cor, out);
}